// Round 1
// baseline (583.015 us; speedup 1.0000x reference)
//
#include <hip/hip_runtime.h>

// PlasticSynapse elementwise update:
//   new_w = clip(baseline*ALPHA + w*(1-ALPHA)
//                + R[b] * |kappa[o,i]| * (post[b,o]*pre[b,i] + SIGMA*noise),
//                0, 1)
// Shapes: w,noise,out: (B,OUT,IN); baseline,kappa: (OUT,IN); pre: (B,IN);
//         post: (B,OUT); R: (B,1,1).  B=64, OUT=1024, IN=1024, all fp32.
// Memory-bound: ~776 MB total HBM traffic -> ~123 us roofline at 6.3 TB/s.

constexpr int B_DIM  = 64;
constexpr int OUT_D  = 1024;
constexpr int IN_D   = 1024;
constexpr int IN4    = IN_D / 4;            // 256 float4 per row
constexpr float ALPHA  = 0.01f;             // DT_W / TAU_W
constexpr float ONE_MA = 1.0f - ALPHA;      // 0.99
constexpr float SIGMA  = 0.14142135623730951f; // sqrt(2/ALPHA)*0.01

__global__ __launch_bounds__(256)
void PlasticSynapse_69466801045994_kernel(
    const float4* __restrict__ w,
    const float4* __restrict__ baseline,
    const float*  __restrict__ R,
    const float4* __restrict__ pre,
    const float*  __restrict__ post,
    const float4* __restrict__ kappa,
    const float4* __restrict__ noise,
    float4*       __restrict__ out)
{
    // Exactly B*OUT*IN4 = 16,777,216 threads launched; no bounds check needed.
    const int idx = blockIdx.x * blockDim.x + threadIdx.x;

    // Decode (b, o, i4). IN4 and OUT_D are powers of two -> shifts/ands.
    const int i4 = idx & (IN4 - 1);
    const int bo = idx >> 8;                 // idx / IN4
    const int o  = bo & (OUT_D - 1);
    const int b  = bo >> 10;                 // bo / OUT_D

    const int oi = o * IN4 + i4;             // index into (OUT,IN) tensors

    const float4 wv = w[idx];
    const float4 nv = noise[idx];
    const float4 bl = baseline[oi];
    const float4 kp = kappa[oi];
    const float4 pr = pre[b * IN4 + i4];
    const float  po = post[b * OUT_D + o];
    const float  r  = R[b];

    float4 res;
    {
        float lr = r * fabsf(kp.x);
        float v  = bl.x * ALPHA + wv.x * ONE_MA + lr * (po * pr.x + SIGMA * nv.x);
        res.x = fminf(fmaxf(v, 0.0f), 1.0f);
    }
    {
        float lr = r * fabsf(kp.y);
        float v  = bl.y * ALPHA + wv.y * ONE_MA + lr * (po * pr.y + SIGMA * nv.y);
        res.y = fminf(fmaxf(v, 0.0f), 1.0f);
    }
    {
        float lr = r * fabsf(kp.z);
        float v  = bl.z * ALPHA + wv.z * ONE_MA + lr * (po * pr.z + SIGMA * nv.z);
        res.z = fminf(fmaxf(v, 0.0f), 1.0f);
    }
    {
        float lr = r * fabsf(kp.w);
        float v  = bl.w * ALPHA + wv.w * ONE_MA + lr * (po * pr.w + SIGMA * nv.w);
        res.w = fminf(fmaxf(v, 0.0f), 1.0f);
    }

    out[idx] = res;
}

extern "C" void kernel_launch(void* const* d_in, const int* in_sizes, int n_in,
                              void* d_out, int out_size, void* d_ws, size_t ws_size,
                              hipStream_t stream) {
    // setup_inputs() dict order: w, baseline, R, pre, post, kappa, noise
    const float4* w        = (const float4*)d_in[0];
    const float4* baseline = (const float4*)d_in[1];
    const float*  R        = (const float*) d_in[2];
    const float4* pre      = (const float4*)d_in[3];
    const float*  post     = (const float*) d_in[4];
    const float4* kappa    = (const float4*)d_in[5];
    const float4* noise    = (const float4*)d_in[6];
    float4*       out      = (float4*)d_out;

    const int total_vec = B_DIM * OUT_D * IN4;   // 16,777,216
    const int block = 256;
    const int grid  = total_vec / block;         // 65,536

    PlasticSynapse_69466801045994_kernel<<<grid, block, 0, stream>>>(
        w, baseline, R, pre, post, kappa, noise, out);
}